// Round 10
// baseline (171.457 us; speedup 1.0000x reference)
//
#include <hip/hip_runtime.h>
#include <hip/hip_bf16.h>

// MoLoRA = base linear + top-2 routed LoRA.
//   Abuf[T,2176] = [ bf16(x) | bf16(alpha*cw*(x@A2^T)) ]      (A2 = A_w as [128,2048])
//   Bfull[O,2176] = [ bf16(W) | bf16(B2^T) ]   (B2[e*16+r,o]=B_w[e,o,r])
//   out[T,O] = Abuf @ Bfull^T     -- single bf16 MFMA GEMM, K=2176
// T=4096, H=2048, O=2048, E=8, R=16, Kaug=2176.
//
// R1: XOR k-chunk LDS swizzle -> bank conflicts 1.34e7 -> 0.
// R5: GEMM 128x128, 2 blocks/CU + counted vmcnt: 40.6us, Mfma 35.4%. KEEP.
// R6-R11 router history: 4-wave serial ~37, 8-wave serial ~37-40, wave-split
//   57.8, ILP-interleave 43.0 (measured). EVERY 1-block/CU structure lands
//   ~40us with ~90% issue-idle -> intra-block arrangement is not the lever;
//   co-residency is (same lesson as GEMM R4->R5).
// R12: router at 2 blocks/CU. 8 tokens/block, xs[8][2056]=34KB, grid 512,
//   256 thr (4 waves; 8 waves/CU as TWO independent barrier groups).
//   p2: 8 tok x 32 slices x 64 cols, same shfl_xor tree, red[4][8][8].
//   p3: 2 experts/wave, M=16 MFMA reads xs[m&7] (rows 8-15 duplicate),
//   p4 stores only trow<8. A2 L2 traffic 2x (256MB ~ 7.4us equiv) accepted.
//   prep/GEMM byte-identical to R8/R5 best.

typedef __bf16 bf16x8 __attribute__((ext_vector_type(8)));
typedef float f32x4 __attribute__((ext_vector_type(4)));

__device__ __forceinline__ __bf16 f2bf(float f) { return (__bf16)f; }  // RNE (v_cvt_pk_bf16_f32)

__device__ __forceinline__ void ld_lds16(const void* g, void* l) {
  __builtin_amdgcn_global_load_lds((__attribute__((address_space(1))) void*)g,
                                   (__attribute__((address_space(3))) void*)l,
                                   16, 0, 0);
}

// ---------------- prep: W->Bfull[:,0:2048], A_w->A2, B_w->Bfull[:,2048:] ----
__global__ void prep_kernel(const float* __restrict__ W, const float* __restrict__ Aw,
                            const float* __restrict__ Bw, __bf16* __restrict__ Bfull,
                            __bf16* __restrict__ A2) {
  const int b = blockIdx.x, tid = threadIdx.x;
  if (b < 2176) {
    const float* src = (b < 2048) ? (W + (size_t)b * 2048)
                                  : (Aw + (size_t)(b - 2048) * 2048);
    __bf16* dst = (b < 2048) ? (Bfull + (size_t)b * 2176)
                             : (A2 + (size_t)(b - 2048) * 2048);
    const int c = tid * 8;
    float4 a = *(const float4*)(src + c);
    float4 d = *(const float4*)(src + c + 4);
    bf16x8 v;
    v[0] = f2bf(a.x); v[1] = f2bf(a.y); v[2] = f2bf(a.z); v[3] = f2bf(a.w);
    v[4] = f2bf(d.x); v[5] = f2bf(d.y); v[6] = f2bf(d.z); v[7] = f2bf(d.w);
    *(bf16x8*)(dst + c) = v;
  } else {
    // pack B_w [E,O,R] -> Bfull[o, 2048 + e*16 + r]
    const int idx = (b - 2176) * 256 + tid;  // 0..16383
    const int e = idx >> 11, o = idx & 2047;
    const float4* s = (const float4*)(Bw + ((size_t)e * 2048 + o) * 16);
    float4 v0 = s[0], v1 = s[1], v2 = s[2], v3 = s[3];
    __bf16* d = Bfull + (size_t)o * 2176 + 2048 + e * 16;
    bf16x8 lo, hi;
    lo[0] = f2bf(v0.x); lo[1] = f2bf(v0.y); lo[2] = f2bf(v0.z); lo[3] = f2bf(v0.w);
    lo[4] = f2bf(v1.x); lo[5] = f2bf(v1.y); lo[6] = f2bf(v1.z); lo[7] = f2bf(v1.w);
    hi[0] = f2bf(v2.x); hi[1] = f2bf(v2.y); hi[2] = f2bf(v2.z); hi[3] = f2bf(v2.w);
    hi[4] = f2bf(v3.x); hi[5] = f2bf(v3.y); hi[6] = f2bf(v3.z); hi[7] = f2bf(v3.w);
    *(bf16x8*)d = lo;
    *(bf16x8*)(d + 8) = hi;
  }
}

// ---------------- router + LoRA-down (t2): 8 tokens/block, 2 blocks/CU ----------------
// grid 512, 256 threads (4 waves). Two independent barrier groups per CU
// overlap each other's latency stalls. Phases = R8-verified serial structure.
__global__ __launch_bounds__(256) void router_t2(
    const float* __restrict__ x, const float* __restrict__ gw,
    const __bf16* __restrict__ A2, __bf16* __restrict__ Abuf) {
  __shared__ __align__(16) __bf16 xs[8][2056];  // 32.9 KB, +8 pad
  __shared__ float red[4][8][8];
  __shared__ float cws[8][8];
  const int tid = threadIdx.x;
  const int wave = tid >> 6, lane = tid & 63;
  const int t0 = blockIdx.x * 8;

  // ---- phase 1: one token-row per iteration, fully coalesced ----
#pragma unroll 4
  for (int i = 0; i < 8; ++i) {
    const float* xr = x + (size_t)(t0 + i) * 2048 + tid * 8;
    float4 a = *(const float4*)xr;
    float4 b = *(const float4*)(xr + 4);
    bf16x8 v;
    v[0] = f2bf(a.x); v[1] = f2bf(a.y); v[2] = f2bf(a.z); v[3] = f2bf(a.w);
    v[4] = f2bf(b.x); v[5] = f2bf(b.y); v[6] = f2bf(b.z); v[7] = f2bf(b.w);
    *(bf16x8*)(Abuf + (size_t)(t0 + i) * 2176 + tid * 8) = v;
    *(bf16x8*)&xs[i][tid * 8] = v;
  }
  __syncthreads();

  // ---- phase 2: logits; 8 tokens x 32 slices x 64 cols ----
  const int tok = tid & 7, slc = tid >> 3;  // slc in [0,32)
  const int c0 = slc * 64;
  float acc[8] = {0, 0, 0, 0, 0, 0, 0, 0};
  for (int j8 = 0; j8 < 8; ++j8) {
    bf16x8 xv = *(const bf16x8*)&xs[tok][c0 + j8 * 8];
    float xf[8];
#pragma unroll
    for (int j = 0; j < 8; ++j) xf[j] = (float)xv[j];
#pragma unroll
    for (int e = 0; e < 8; ++e) {
      float4 g0 = *(const float4*)(gw + e * 2048 + c0 + j8 * 8);
      float4 g1 = *(const float4*)(gw + e * 2048 + c0 + j8 * 8 + 4);
      acc[e] += xf[0] * g0.x + xf[1] * g0.y + xf[2] * g0.z + xf[3] * g0.w +
                xf[4] * g1.x + xf[5] * g1.y + xf[6] * g1.z + xf[7] * g1.w;
    }
  }
  // sum over the wave's 8 slice-groups (lane bits 3,4,5); token = lane&7
#pragma unroll
  for (int e = 0; e < 8; ++e) {
    acc[e] += __shfl_xor(acc[e], 8);
    acc[e] += __shfl_xor(acc[e], 16);
    acc[e] += __shfl_xor(acc[e], 32);
  }
  if (lane < 8) {
#pragma unroll
    for (int e = 0; e < 8; ++e) red[wave][lane][e] = acc[e];
  }
  __syncthreads();
  if (tid < 8) {
    float lg[8];
#pragma unroll
    for (int e = 0; e < 8; ++e)
      lg[e] = red[0][tid][e] + red[1][tid][e] + red[2][tid][e] + red[3][tid][e];
    int a = 0;
    for (int e = 1; e < 8; ++e) if (lg[e] > lg[a]) a = e;
    int b = (a == 0) ? 1 : 0;
    for (int e = 0; e < 8; ++e) if (e != a && lg[e] > lg[b]) b = e;
    const float d = __expf(lg[b] - lg[a]);
    float o[8] = {0, 0, 0, 0, 0, 0, 0, 0};
    o[a] = 1.0f / (1.0f + d);
    o[b] = d / (1.0f + d);
#pragma unroll
    for (int e = 0; e < 8; ++e) cws[tid][e] = o[e];
  }
  __syncthreads();

  // ---- phase 3: t = xs @ A2^T; 2 experts/wave; M rows 8-15 duplicate 0-7 ----
  const int m = lane & 15, q = lane >> 4;
  const int nt0 = wave * 2;
  f32x4 tacc[2] = {};
  for (int ks = 0; ks < 64; ++ks) {
    bf16x8 af = *(const bf16x8*)&xs[m & 7][ks * 32 + q * 8];
#pragma unroll
    for (int h = 0; h < 2; ++h) {
      bf16x8 bfg = *(const bf16x8*)(A2 + (size_t)((nt0 + h) * 16 + m) * 2048 +
                                    ks * 32 + q * 8);
      tacc[h] = __builtin_amdgcn_mfma_f32_16x16x32_bf16(af, bfg, tacc[h], 0, 0, 0);
    }
  }
  // ---- phase 4: scale + store valid rows only (trow = q*4+rg < 8 <=> q < 2) ----
  if (q < 2) {
#pragma unroll
    for (int h = 0; h < 2; ++h) {
      const int nt = nt0 + h;
#pragma unroll
      for (int rg = 0; rg < 4; ++rg) {
        const int trow = q * 4 + rg;  // 0..7
        const float s = tacc[h][rg] * 16.0f * cws[trow][nt];
        Abuf[(size_t)(t0 + trow) * 2176 + 2048 + nt * 16 + m] = f2bf(s);
      }
    }
  }
}

// ---------------- multi-block MFMA GEMM (unchanged from R5/R8 best) ----------------
// 128x128 tile, BK=64, 256 threads = 4 waves (2x2 of 64x64). 2 buffers x 32KB
// = 64KB LDS -> 2 blocks/CU co-resident. Grid 512 = exactly 2/CU. Counted
// vmcnt(8) keeps next tile's 8 gloads in flight across the barrier.
__global__ __launch_bounds__(256, 2) void mfma_gemm_bt4(
    const __bf16* __restrict__ A, const __bf16* __restrict__ B,
    float* __restrict__ C, int lda, int ldb, int ldc, int kiters) {
  __shared__ __align__(16) __bf16 lds[2 * 16384];  // 64 KB: [buf][A 8192 | B 8192]
  const int tid = threadIdx.x;
  const int wave = tid >> 6;
  const int lane = tid & 63;

  // XCD chunking: 512 wgs, 8 XCDs -> 64 consecutive ids per XCD, shaped 8Mx8N.
  const int wg = blockIdx.x + (blockIdx.y << 5);  // 32 M-tiles x 16 N-tiles
  const int xcd = wg & 7, loc = wg >> 3;          // loc 0..63
  const int tm = ((xcd & 3) * 8 + (loc >> 3)) * 128;
  const int tn = ((xcd >> 2) * 8 + (loc & 7)) * 128;

  const int srow = lane >> 3;                 // row within 8-row staging chunk
  const int skoff = ((lane & 7) ^ srow) * 8;  // XOR-swizzled k offset (elems)

  const int wr = wave >> 1, wc = wave & 1;    // 2x2 wave grid of 64x64 tiles
  const int rlo = lane & 7;
  const int rb3 = (lane >> 3) & 1;
  const int qb = lane >> 4;

  f32x4 acc[4][4] = {};

  // stage tile kt into buffer buf: 32 chunks ([8 rows][64 k] each), 8/wave
  auto stage = [&](int buf, int kt) {
    const int kc = kt * 64;
    __bf16* Ls = lds + buf * 16384;
#pragma unroll
    for (int r = 0; r < 4; ++r) {
      const int ch = wave + r * 4;  // A chunks 0..15 (rows tm..tm+127)
      ld_lds16(A + (size_t)(tm + ch * 8 + srow) * lda + kc + skoff, &Ls[ch * 512]);
    }
#pragma unroll
    for (int r = 0; r < 4; ++r) {
      const int ch = wave + r * 4;  // B chunks 0..15 (rows tn..tn+127)
      ld_lds16(B + (size_t)(tn + ch * 8 + srow) * ldb + kc + skoff,
               &Ls[8192 + ch * 512]);
    }
  };

  stage(0, 0);  // prologue: tile 0 in flight

  for (int kt = 0; kt < kiters; ++kt) {
    const int cb = kt & 1;
    if (kt + 1 < kiters) {
      stage(cb ^ 1, kt + 1);  // overwrites buffer read at kt-1 (barrier-safe)
      asm volatile("s_waitcnt vmcnt(8)" ::: "memory");  // tile kt landed
    } else {
      asm volatile("s_waitcnt vmcnt(0)" ::: "memory");
    }
    __builtin_amdgcn_s_barrier();

    const __bf16* As = lds + cb * 16384;
    const __bf16* Bs = As + 8192;
#pragma unroll
    for (int ks = 0; ks < 2; ++ks) {
      bf16x8 af[4], bfg[4];
      const int q8 = ((ks * 4 + qb) ^ rlo) * 8;
#pragma unroll
      for (int i = 0; i < 4; ++i) {
        const int rh = wr * 8 + i * 2 + rb3;
        af[i] = *(const bf16x8*)&As[rh * 512 + rlo * 64 + q8];
      }
#pragma unroll
      for (int j = 0; j < 4; ++j) {
        const int rh = wc * 8 + j * 2 + rb3;
        bfg[j] = *(const bf16x8*)&Bs[rh * 512 + rlo * 64 + q8];
      }
      __builtin_amdgcn_s_setprio(1);
#pragma unroll
      for (int i = 0; i < 4; ++i)
#pragma unroll
        for (int j = 0; j < 4; ++j)
          acc[i][j] =
              __builtin_amdgcn_mfma_f32_16x16x32_bf16(af[i], bfg[j], acc[i][j], 0, 0, 0);
      __builtin_amdgcn_s_setprio(0);
    }
    __builtin_amdgcn_s_barrier();  // all reads of buf cb done before next overwrite
  }

  // C/D layout: col = lane&15, row = (lane>>4)*4 + reg
  const int crow0 = tm + wr * 64 + (lane >> 4) * 4;
  const int ccol0 = tn + wc * 64 + (lane & 15);
#pragma unroll
  for (int i = 0; i < 4; ++i)
#pragma unroll
    for (int j = 0; j < 4; ++j)
#pragma unroll
      for (int rg = 0; rg < 4; ++rg)
        C[(size_t)(crow0 + i * 16 + rg) * ldc + ccol0 + j * 16] = acc[i][j][rg];
}

extern "C" void kernel_launch(void* const* d_in, const int* in_sizes, int n_in,
                              void* d_out, int out_size, void* d_ws, size_t ws_size,
                              hipStream_t stream) {
  const float* x = (const float*)d_in[0];       // [2,2048,2048] -> [4096,2048]
  const float* weight = (const float*)d_in[1];  // [2048,2048]
  const float* gate_w = (const float*)d_in[2];  // [8,2048]
  const float* A_w = (const float*)d_in[3];     // [8,16,2048] == [128,2048]
  const float* B_w = (const float*)d_in[4];     // [8,2048,16]
  float* out = (float*)d_out;                   // [4096,2048]

  char* ws = (char*)d_ws;
  __bf16* Abuf = (__bf16*)ws;                // [4096,2176] bf16 = 17,825,792 B
  __bf16* Bfull = (__bf16*)(ws + 17825792);  // [2048,2176] bf16 =  8,912,896 B
  __bf16* A2 = (__bf16*)(ws + 26738688);     // [128,2048]  bf16 =    524,288 B

  // 1. prep: W -> Bfull[:,0:2048]; A_w -> A2; B_w -> Bfull[:,2048:2176]
  prep_kernel<<<2240, 256, 0, stream>>>(weight, A_w, B_w, Bfull, A2);
  // 2. router + x->bf16 + LoRA-down (t2): 8 tokens/block, 2 blocks/CU
  router_t2<<<512, 256, 0, stream>>>(x, gate_w, A2, Abuf);
  // 3. out = Abuf @ Bfull^T  (K=2176 fuses base + LoRA-up)
  mfma_gemm_bt4<<<dim3(32, 16), 256, 0, stream>>>(Abuf, Bfull, out, 2176, 2176,
                                                  2048, 34);
}

// Round 11
// 158.719 us; speedup vs baseline: 1.0803x; 1.0803x over previous
//
#include <hip/hip_runtime.h>
#include <hip/hip_bf16.h>

// MoLoRA = base linear + top-2 routed LoRA.
//   Abuf[T,2176] = [ bf16(x) | bf16(alpha*cw*(x@A2^T)) ]      (A2 = A_w as [128,2048])
//   Bfull[O,2176] = [ bf16(W) | bf16(B2^T) ]   (B2[e*16+r,o]=B_w[e,o,r])
//   out[T,O] = Abuf @ Bfull^T     -- single bf16 MFMA GEMM, K=2176
// T=4096, H=2048, O=2048, E=8, R=16, Kaug=2176.
//
// FINAL CONFIG = R8 (best measured: 158.97us), restored byte-exact after R9-R12
// all regressed. Component ledger (measured):
//   prep  ~6.5us  (BW floor for 36MB)
//   router ~37-40us (latency floor: 6 structural variants span 37-52us, all
//                   <9% VALUBusy, <1TB/s -- pinned regardless of occupancy/
//                   wave-count/block-count; residual attributed to concurrent
//                   harness fill traffic saturating HBM)
//   GEMM  40.6us @ MfmaUtil 35.4% (2-barrier plateau; m201-class schedule
//                   structurally excluded at this M*N: only 128 256^2-blocks)
//   fills ~75us   (harness-fixed poison of 256MB workspace + out)
//
// R1: XOR k-chunk LDS swizzle -> bank conflicts 1.34e7 -> 0.
// R5: GEMM 128x128, 2 blocks/CU co-resident + counted vmcnt(8). KEEP.
// R8: router 512 thr (8 waves, 2/SIMD), serial 4-phase monolith. KEEP.

typedef __bf16 bf16x8 __attribute__((ext_vector_type(8)));
typedef float f32x4 __attribute__((ext_vector_type(4)));

__device__ __forceinline__ __bf16 f2bf(float f) { return (__bf16)f; }  // RNE (v_cvt_pk_bf16_f32)

__device__ __forceinline__ void ld_lds16(const void* g, void* l) {
  __builtin_amdgcn_global_load_lds((__attribute__((address_space(1))) void*)g,
                                   (__attribute__((address_space(3))) void*)l,
                                   16, 0, 0);
}

// ---------------- prep: W->Bfull[:,0:2048], A_w->A2, B_w->Bfull[:,2048:] ----
__global__ void prep_kernel(const float* __restrict__ W, const float* __restrict__ Aw,
                            const float* __restrict__ Bw, __bf16* __restrict__ Bfull,
                            __bf16* __restrict__ A2) {
  const int b = blockIdx.x, tid = threadIdx.x;
  if (b < 2176) {
    const float* src = (b < 2048) ? (W + (size_t)b * 2048)
                                  : (Aw + (size_t)(b - 2048) * 2048);
    __bf16* dst = (b < 2048) ? (Bfull + (size_t)b * 2176)
                             : (A2 + (size_t)(b - 2048) * 2048);
    const int c = tid * 8;
    float4 a = *(const float4*)(src + c);
    float4 d = *(const float4*)(src + c + 4);
    bf16x8 v;
    v[0] = f2bf(a.x); v[1] = f2bf(a.y); v[2] = f2bf(a.z); v[3] = f2bf(a.w);
    v[4] = f2bf(d.x); v[5] = f2bf(d.y); v[6] = f2bf(d.z); v[7] = f2bf(d.w);
    *(bf16x8*)(dst + c) = v;
  } else {
    // pack B_w [E,O,R] -> Bfull[o, 2048 + e*16 + r]
    const int idx = (b - 2176) * 256 + tid;  // 0..16383
    const int e = idx >> 11, o = idx & 2047;
    const float4* s = (const float4*)(Bw + ((size_t)e * 2048 + o) * 16);
    float4 v0 = s[0], v1 = s[1], v2 = s[2], v3 = s[3];
    __bf16* d = Bfull + (size_t)o * 2176 + 2048 + e * 16;
    bf16x8 lo, hi;
    lo[0] = f2bf(v0.x); lo[1] = f2bf(v0.y); lo[2] = f2bf(v0.z); lo[3] = f2bf(v0.w);
    lo[4] = f2bf(v1.x); lo[5] = f2bf(v1.y); lo[6] = f2bf(v1.z); lo[7] = f2bf(v1.w);
    hi[0] = f2bf(v2.x); hi[1] = f2bf(v2.y); hi[2] = f2bf(v2.z); hi[3] = f2bf(v2.w);
    hi[4] = f2bf(v3.x); hi[5] = f2bf(v3.y); hi[6] = f2bf(v3.z); hi[7] = f2bf(v3.w);
    *(bf16x8*)d = lo;
    *(bf16x8*)(d + 8) = hi;
  }
}

// ---------------- fused router + LoRA-down (t2), 512 threads ----------------
// 16 tokens/block, grid 256, 8 waves (2/SIMD). Serial 4-phase structure.
__global__ __launch_bounds__(512) void router_t2(
    const float* __restrict__ x, const float* __restrict__ gw,
    const __bf16* __restrict__ A2, __bf16* __restrict__ Abuf) {
  __shared__ __align__(16) __bf16 xs[16][2056];  // 64.25 KB, +8 pad
  __shared__ float red[8][16][8];
  __shared__ float cws[16][8];
  const int tid = threadIdx.x;
  const int wave = tid >> 6, lane = tid & 63;
  const int t0 = blockIdx.x * 16;

  // ---- phase 1: two token-rows per iteration, fully coalesced ----
  {
    const int half = tid >> 8;        // 0/1: which row of the pair
    const int tid2 = tid & 255;
#pragma unroll 4
    for (int i2 = 0; i2 < 8; ++i2) {
      const int i = i2 * 2 + half;
      const float* xr = x + (size_t)(t0 + i) * 2048 + tid2 * 8;
      float4 a = *(const float4*)xr;
      float4 b = *(const float4*)(xr + 4);
      bf16x8 v;
      v[0] = f2bf(a.x); v[1] = f2bf(a.y); v[2] = f2bf(a.z); v[3] = f2bf(a.w);
      v[4] = f2bf(b.x); v[5] = f2bf(b.y); v[6] = f2bf(b.z); v[7] = f2bf(b.w);
      *(bf16x8*)(Abuf + (size_t)(t0 + i) * 2176 + tid2 * 8) = v;
      *(bf16x8*)&xs[i][tid2 * 8] = v;
    }
  }
  __syncthreads();

  // ---- phase 2: logits from bf16 x; 32 slices of 64 elems per token ----
  const int tok = tid & 15, slc = tid >> 4;  // slc in [0,32)
  const int c0 = slc * 64;
  float acc[8] = {0, 0, 0, 0, 0, 0, 0, 0};
  for (int j8 = 0; j8 < 8; ++j8) {
    bf16x8 xv = *(const bf16x8*)&xs[tok][c0 + j8 * 8];
    float xf[8];
#pragma unroll
    for (int j = 0; j < 8; ++j) xf[j] = (float)xv[j];
#pragma unroll
    for (int e = 0; e < 8; ++e) {
      float4 g0 = *(const float4*)(gw + e * 2048 + c0 + j8 * 8);
      float4 g1 = *(const float4*)(gw + e * 2048 + c0 + j8 * 8 + 4);
      acc[e] += xf[0] * g0.x + xf[1] * g0.y + xf[2] * g0.z + xf[3] * g0.w +
                xf[4] * g1.x + xf[5] * g1.y + xf[6] * g1.z + xf[7] * g1.w;
    }
  }
  // lanes hold 4 slices per wave; combine -> lane<16, then LDS across 8 waves
#pragma unroll
  for (int e = 0; e < 8; ++e) {
    acc[e] += __shfl_down(acc[e], 16);
    acc[e] += __shfl_down(acc[e], 32);
  }
  if (lane < 16) {
#pragma unroll
    for (int e = 0; e < 8; ++e) red[wave][lane][e] = acc[e];
  }
  __syncthreads();
  if (tid < 16) {
    float lg[8];
#pragma unroll
    for (int e = 0; e < 8; ++e)
      lg[e] = red[0][tid][e] + red[1][tid][e] + red[2][tid][e] + red[3][tid][e] +
              red[4][tid][e] + red[5][tid][e] + red[6][tid][e] + red[7][tid][e];
    int a = 0;
    for (int e = 1; e < 8; ++e) if (lg[e] > lg[a]) a = e;
    int b = (a == 0) ? 1 : 0;
    for (int e = 0; e < 8; ++e) if (e != a && lg[e] > lg[b]) b = e;
    const float d = __expf(lg[b] - lg[a]);
    float o[8] = {0, 0, 0, 0, 0, 0, 0, 0};
    o[a] = 1.0f / (1.0f + d);
    o[b] = d / (1.0f + d);
#pragma unroll
    for (int e = 0; e < 8; ++e) cws[tid][e] = o[e];
  }
  __syncthreads();

  // ---- phase 3: t = xs @ A2^T, one expert per wave ----
  const int m = lane & 15, q = lane >> 4;
  const int nt = wave;  // expert index
  f32x4 tacc = {};
  for (int ks = 0; ks < 64; ++ks) {
    bf16x8 af = *(const bf16x8*)&xs[m][ks * 32 + q * 8];
    bf16x8 bfg = *(const bf16x8*)(A2 + (size_t)(nt * 16 + m) * 2048 +
                                  ks * 32 + q * 8);
    tacc = __builtin_amdgcn_mfma_f32_16x16x32_bf16(af, bfg, tacc, 0, 0, 0);
  }
  // ---- phase 4: scale + store. C layout: col=lane&15, row=q*4+reg ----
#pragma unroll
  for (int rg = 0; rg < 4; ++rg) {
    const int trow = q * 4 + rg;
    const float s = tacc[rg] * 16.0f * cws[trow][nt];
    Abuf[(size_t)(t0 + trow) * 2176 + 2048 + nt * 16 + m] = f2bf(s);
  }
}

// ---------------- multi-block MFMA GEMM (R5 best) ----------------
// 128x128 tile, BK=64, 256 threads = 4 waves (2x2 of 64x64). 2 buffers x 32KB
// = 64KB LDS -> 2 blocks/CU co-resident. Grid 512 = exactly 2/CU. Counted
// vmcnt(8) keeps next tile's 8 gloads in flight across the barrier.
__global__ __launch_bounds__(256, 2) void mfma_gemm_bt4(
    const __bf16* __restrict__ A, const __bf16* __restrict__ B,
    float* __restrict__ C, int lda, int ldb, int ldc, int kiters) {
  __shared__ __align__(16) __bf16 lds[2 * 16384];  // 64 KB: [buf][A 8192 | B 8192]
  const int tid = threadIdx.x;
  const int wave = tid >> 6;
  const int lane = tid & 63;

  // XCD chunking: 512 wgs, 8 XCDs -> 64 consecutive ids per XCD, shaped 8Mx8N.
  const int wg = blockIdx.x + (blockIdx.y << 5);  // 32 M-tiles x 16 N-tiles
  const int xcd = wg & 7, loc = wg >> 3;          // loc 0..63
  const int tm = ((xcd & 3) * 8 + (loc >> 3)) * 128;
  const int tn = ((xcd >> 2) * 8 + (loc & 7)) * 128;

  const int srow = lane >> 3;                 // row within 8-row staging chunk
  const int skoff = ((lane & 7) ^ srow) * 8;  // XOR-swizzled k offset (elems)

  const int wr = wave >> 1, wc = wave & 1;    // 2x2 wave grid of 64x64 tiles
  const int rlo = lane & 7;
  const int rb3 = (lane >> 3) & 1;
  const int qb = lane >> 4;

  f32x4 acc[4][4] = {};

  // stage tile kt into buffer buf: 32 chunks ([8 rows][64 k] each), 8/wave
  auto stage = [&](int buf, int kt) {
    const int kc = kt * 64;
    __bf16* Ls = lds + buf * 16384;
#pragma unroll
    for (int r = 0; r < 4; ++r) {
      const int ch = wave + r * 4;  // A chunks 0..15 (rows tm..tm+127)
      ld_lds16(A + (size_t)(tm + ch * 8 + srow) * lda + kc + skoff, &Ls[ch * 512]);
    }
#pragma unroll
    for (int r = 0; r < 4; ++r) {
      const int ch = wave + r * 4;  // B chunks 0..15 (rows tn..tn+127)
      ld_lds16(B + (size_t)(tn + ch * 8 + srow) * ldb + kc + skoff,
               &Ls[8192 + ch * 512]);
    }
  };

  stage(0, 0);  // prologue: tile 0 in flight

  for (int kt = 0; kt < kiters; ++kt) {
    const int cb = kt & 1;
    if (kt + 1 < kiters) {
      stage(cb ^ 1, kt + 1);  // overwrites buffer read at kt-1 (barrier-safe)
      asm volatile("s_waitcnt vmcnt(8)" ::: "memory");  // tile kt landed
    } else {
      asm volatile("s_waitcnt vmcnt(0)" ::: "memory");
    }
    __builtin_amdgcn_s_barrier();

    const __bf16* As = lds + cb * 16384;
    const __bf16* Bs = As + 8192;
#pragma unroll
    for (int ks = 0; ks < 2; ++ks) {
      bf16x8 af[4], bfg[4];
      const int q8 = ((ks * 4 + qb) ^ rlo) * 8;
#pragma unroll
      for (int i = 0; i < 4; ++i) {
        const int rh = wr * 8 + i * 2 + rb3;
        af[i] = *(const bf16x8*)&As[rh * 512 + rlo * 64 + q8];
      }
#pragma unroll
      for (int j = 0; j < 4; ++j) {
        const int rh = wc * 8 + j * 2 + rb3;
        bfg[j] = *(const bf16x8*)&Bs[rh * 512 + rlo * 64 + q8];
      }
      __builtin_amdgcn_s_setprio(1);
#pragma unroll
      for (int i = 0; i < 4; ++i)
#pragma unroll
        for (int j = 0; j < 4; ++j)
          acc[i][j] =
              __builtin_amdgcn_mfma_f32_16x16x32_bf16(af[i], bfg[j], acc[i][j], 0, 0, 0);
      __builtin_amdgcn_s_setprio(0);
    }
    __builtin_amdgcn_s_barrier();  // all reads of buf cb done before next overwrite
  }

  // C/D layout: col = lane&15, row = (lane>>4)*4 + reg
  const int crow0 = tm + wr * 64 + (lane >> 4) * 4;
  const int ccol0 = tn + wc * 64 + (lane & 15);
#pragma unroll
  for (int i = 0; i < 4; ++i)
#pragma unroll
    for (int j = 0; j < 4; ++j)
#pragma unroll
      for (int rg = 0; rg < 4; ++rg)
        C[(size_t)(crow0 + i * 16 + rg) * ldc + ccol0 + j * 16] = acc[i][j][rg];
}

extern "C" void kernel_launch(void* const* d_in, const int* in_sizes, int n_in,
                              void* d_out, int out_size, void* d_ws, size_t ws_size,
                              hipStream_t stream) {
  const float* x = (const float*)d_in[0];       // [2,2048,2048] -> [4096,2048]
  const float* weight = (const float*)d_in[1];  // [2048,2048]
  const float* gate_w = (const float*)d_in[2];  // [8,2048]
  const float* A_w = (const float*)d_in[3];     // [8,16,2048] == [128,2048]
  const float* B_w = (const float*)d_in[4];     // [8,2048,16]
  float* out = (float*)d_out;                   // [4096,2048]

  char* ws = (char*)d_ws;
  __bf16* Abuf = (__bf16*)ws;                // [4096,2176] bf16 = 17,825,792 B
  __bf16* Bfull = (__bf16*)(ws + 17825792);  // [2048,2176] bf16 =  8,912,896 B
  __bf16* A2 = (__bf16*)(ws + 26738688);     // [128,2048]  bf16 =    524,288 B

  // 1. prep: W -> Bfull[:,0:2048]; A_w -> A2; B_w -> Bfull[:,2048:2176]
  prep_kernel<<<2240, 256, 0, stream>>>(weight, A_w, B_w, Bfull, A2);
  // 2. router + x->bf16 + LoRA-down (t2) into Abuf  (512 threads, 8 waves)
  router_t2<<<256, 512, 0, stream>>>(x, gate_w, A2, Abuf);
  // 3. out = Abuf @ Bfull^T  (K=2176 fuses base + LoRA-up)
  mfma_gemm_bt4<<<dim3(32, 16), 256, 0, stream>>>(Abuf, Bfull, out, 2176, 2176,
                                                  2048, 34);
}